// Round 13
// baseline (119.291 us; speedup 1.0000x reference)
//
#include <hip/hip_runtime.h>
#include <hip/hip_bf16.h>
#include <math.h>

#define DIM 512
#define HEADS 8
#define HD 64
#define ROWS_TOTAL 8192   // 4 * 2048
#define SEQ 2048
#define NSLICE 16         // m-tiles (128 rows) per batch = KV partial slices

typedef __hip_bfloat16 bf16;
typedef __bf16 bf16x8 __attribute__((ext_vector_type(8)));
typedef float f32x4 __attribute__((ext_vector_type(4)));

__device__ __forceinline__ float elu1(float x) {
    return x > 0.f ? x + 1.f : __expf(x);
}
__device__ __forceinline__ void gl16(const void* g, void* l) {
    __builtin_amdgcn_global_load_lds(
        (const __attribute__((address_space(1))) void*)g,
        (__attribute__((address_space(3))) void*)l, 16, 0, 0);
}
__device__ __forceinline__ unsigned short f2bu(float v) {
    bf16 t = __float2bfloat16(v);
    return *(unsigned short*)&t;
}

// ---- prep: blocks 0..2047 transpose+convert weights; 2048..4095 LN1(x)+xb -
// WqkvT rows: [0,512) = Wq^T; row 512 + h*128 + i: i<64 -> Wk^T[h*64+i],
// i>=64 -> Wv^T[h*64+i-64]  (one 128-wide GEMM block = head h's K|V cols)
__global__ __launch_bounds__(256) void prep_kernel(
    const float* __restrict__ Wq, const float* __restrict__ Wk,
    const float* __restrict__ Wv, const float* __restrict__ Wo,
    const float* __restrict__ W1, const float* __restrict__ W2,
    bf16* WqkvT, bf16* WoT, bf16* W1T, bf16* W2T,
    const float* __restrict__ x, const float* __restrict__ g,
    const float* __restrict__ b, bf16* __restrict__ xout,
    bf16* __restrict__ xb)
{
    __shared__ float t[32][33];
    int bx = blockIdx.x;
    if (bx >= 2048) {
        int row  = (bx - 2048) * 4 + (threadIdx.x >> 6);
        int lane = threadIdx.x & 63;
        const float* xr = x + (size_t)row * DIM + lane * 8;
        float4 v1 = *(const float4*)xr;
        float4 v2 = *(const float4*)(xr + 4);
        float f[8] = {v1.x, v1.y, v1.z, v1.w, v2.x, v2.y, v2.z, v2.w};
        int c = lane * 8;
        bf16 rb[8];
#pragma unroll
        for (int j = 0; j < 8; ++j) rb[j] = __float2bfloat16(f[j]);
        *(uint4*)(xb + (size_t)row * DIM + c) = *(uint4*)rb;
        float s = 0.f, sq = 0.f;
#pragma unroll
        for (int j = 0; j < 8; ++j) { s += f[j]; sq += f[j]*f[j]; }
#pragma unroll
        for (int off = 32; off > 0; off >>= 1) {
            s  += __shfl_xor(s,  off, 64);
            sq += __shfl_xor(sq, off, 64);
        }
        float mean = s * (1.f / DIM);
        float var  = sq * (1.f / DIM) - mean * mean;
        float rstd = rsqrtf(var + 1e-5f);
        float4 ga = *(const float4*)(g + c);
        float4 gb = *(const float4*)(g + c + 4);
        float4 ba = *(const float4*)(b + c);
        float4 bb = *(const float4*)(b + c + 4);
        float gg[8]  = {ga.x,ga.y,ga.z,ga.w,gb.x,gb.y,gb.z,gb.w};
        float bbv[8] = {ba.x,ba.y,ba.z,ba.w,bb.x,bb.y,bb.z,bb.w};
        bf16 ob[8];
#pragma unroll
        for (int j = 0; j < 8; ++j)
            ob[j] = __float2bfloat16((f[j] - mean) * rstd * gg[j] + bbv[j]);
        *(uint4*)(xout + (size_t)row * DIM + c) = *(uint4*)ob;
        return;
    }
    const float* W; bf16* T; int K, N, tk, tn, mode = 0;
    if (bx < 1024) {
        int m = bx >> 8, tix = bx & 255;
        const float* ws_[4] = {Wq, Wk, Wv, Wo};
        W = ws_[m];
        T = (m == 3) ? WoT : WqkvT;
        mode = (m == 1) ? 1 : (m == 2 ? 2 : 0);
        K = 512; N = 512; tn = tix & 15; tk = tix >> 4;
    } else if (bx < 1536) {
        int tix = bx - 1024; W = W1; T = W1T; K = 512; N = 1024; tn = tix & 31; tk = tix >> 5;
    } else {
        int tix = bx - 1536; W = W2; T = W2T; K = 1024; N = 512; tn = tix & 15; tk = tix >> 4;
    }
    int n0 = tn * 32, k0 = tk * 32;
    int tx = threadIdx.x & 31, ty = threadIdx.x >> 5;
#pragma unroll
    for (int i = 0; i < 32; i += 8)
        t[ty + i][tx] = W[(size_t)(k0 + ty + i) * N + n0 + tx];
    __syncthreads();
#pragma unroll
    for (int i = 0; i < 32; i += 8) {
        int n = n0 + ty + i;
        int dr = n;
        if (mode == 1)      dr = 512 + ((n >> 6) << 7) + (n & 63);
        else if (mode == 2) dr = 576 + ((n >> 6) << 7) + (n & 63);
        T[(size_t)dr * K + k0 + tx] = __float2bfloat16(t[tx][ty + i]);
    }
}

// ------- LayerNorm (bf16 in), one wave per row ----------------------------
__global__ __launch_bounds__(256) void ln_kernel(const bf16* __restrict__ xv,
                                                 const float* __restrict__ g,
                                                 const float* __restrict__ b,
                                                 bf16* __restrict__ out)
{
    int row  = blockIdx.x * 4 + (threadIdx.x >> 6);
    int lane = threadIdx.x & 63;
    bf16x8 v = *(const bf16x8*)(xv + (size_t)row * DIM + lane * 8);
    float f[8];
#pragma unroll
    for (int j = 0; j < 8; ++j) f[j] = (float)v[j];
    float s = 0.f, sq = 0.f;
#pragma unroll
    for (int j = 0; j < 8; ++j) { s += f[j]; sq += f[j]*f[j]; }
#pragma unroll
    for (int off = 32; off > 0; off >>= 1) {
        s  += __shfl_xor(s,  off, 64);
        sq += __shfl_xor(sq, off, 64);
    }
    float mean = s * (1.f / DIM);
    float var  = sq * (1.f / DIM) - mean * mean;
    float rstd = rsqrtf(var + 1e-5f);
    int c = lane * 8;
    float4 ga = *(const float4*)(g + c);
    float4 gb = *(const float4*)(g + c + 4);
    float4 ba = *(const float4*)(b + c);
    float4 bb = *(const float4*)(b + c + 4);
    float gg[8]  = {ga.x,ga.y,ga.z,ga.w,gb.x,gb.y,gb.z,gb.w};
    float bbv[8] = {ba.x,ba.y,ba.z,ba.w,bb.x,bb.y,bb.z,bb.w};
    bf16 ob[8];
#pragma unroll
    for (int j = 0; j < 8; ++j)
        ob[j] = __float2bfloat16((f[j] - mean) * rstd * gg[j] + bbv[j]);
    *(uint4*)(out + (size_t)row * DIM + c) = *(uint4*)ob;
}

// ---- fused QKV projection + per-slice KV^T/ksum (K,V never hit HBM) ------
// 2-buffer dbuf; LDS XOR-swizzled via pre-swizzled global src (m173).
// KVT partials stored bf16 (fp32 re-accumulated in attn).
__global__ __launch_bounds__(256) void qkv_kv_kernel(
    const bf16* __restrict__ A, const bf16* __restrict__ Bt,
    const float* __restrict__ bq, const float* __restrict__ bk,
    const float* __restrict__ bv, bf16* __restrict__ Qb,
    bf16* __restrict__ KVTp, float* __restrict__ KSp, float scale)
{
    constexpr int K = 512;
    __shared__ __align__(16) bf16 As[2][128 * 64];
    __shared__ __align__(16) bf16 Bs[2][128 * 64];
    int tid = threadIdx.x;
    int lane = tid & 63, wid = tid >> 6;
    int wr = wid >> 1, wc = wid & 1;
    int cpx = gridDim.x >> 3;
    int work = (blockIdx.x & 7) * cpx + (blockIdx.x >> 3);
    int bx = work % 12, by = work / 12;
    int m0 = by * 128, n0 = bx * 128;
    int sr = tid >> 3;
    int scb = (((tid & 7) << 4) ^ ((sr & 7) << 4)) >> 1;   // swizzled src col (elems)
    const bf16* ga = A  + (size_t)(m0 + sr) * K + scb;
    const bf16* gb = Bt + (size_t)(n0 + sr) * K + scb;
    f32x4 acc[4][4] = {};
    int la = lane & 15, ka = lane >> 4;
    int xo = (la & 7) << 4;                                 // read-side XOR

#pragma unroll
    for (int j = 0; j < 4; ++j) {
        gl16(ga + (size_t)j * 32 * K, &As[0][tid * 8 + j * 2048]);
        gl16(gb + (size_t)j * 32 * K, &Bs[0][tid * 8 + j * 2048]);
    }
    __syncthreads();
    for (int t = 0; t < 8; ++t) {
        int cur = t & 1;
        if (t + 1 < 8) {
            int k0 = (t + 1) << 6;
#pragma unroll
            for (int j = 0; j < 4; ++j) {
                gl16(ga + (size_t)j * 32 * K + k0, &As[cur ^ 1][tid * 8 + j * 2048]);
                gl16(gb + (size_t)j * 32 * K + k0, &Bs[cur ^ 1][tid * 8 + j * 2048]);
            }
        }
        const char* Ab = (const char*)As[cur];
        const char* Bb = (const char*)Bs[cur];
        bf16x8 a[2][4], b[2][4];
#pragma unroll
        for (int kk = 0; kk < 2; ++kk) {
            int kb = (kk * 64 + ka * 16) ^ xo;
#pragma unroll
            for (int m = 0; m < 4; ++m)
                a[kk][m] = *(const bf16x8*)(Ab + (wr * 64 + m * 16 + la) * 128 + kb);
#pragma unroll
            for (int n = 0; n < 4; ++n)
                b[kk][n] = *(const bf16x8*)(Bb + (wc * 64 + n * 16 + la) * 128 + kb);
        }
#pragma unroll
        for (int kk = 0; kk < 2; ++kk)
#pragma unroll
            for (int m = 0; m < 4; ++m)
#pragma unroll
                for (int n = 0; n < 4; ++n)
                    acc[m][n] = __builtin_amdgcn_mfma_f32_16x16x32_bf16(a[kk][m], b[kk][n], acc[m][n], 0, 0, 0);
        __syncthreads();
    }

    int rg = (lane >> 4) * 4;
    if (bx < 4) {
#pragma unroll
        for (int m = 0; m < 4; ++m) {
            int gm = m0 + wr * 64 + m * 16 + rg;
#pragma unroll
            for (int n = 0; n < 4; ++n) {
                int gnl = bx * 128 + wc * 64 + n * 16 + la;
                float bv_ = bq[gnl];
#pragma unroll
                for (int j = 0; j < 4; ++j) {
                    float v = elu1((acc[m][n][j] + bv_) * scale);
                    Qb[(size_t)(gm + j) * 512 + gnl] = __float2bfloat16(v);
                }
            }
        }
    } else {
        // ---- K|V epilogue -> swizzled LDS transpose -> KV^T + ksum ----
        int hh = bx - 4;
        int bb = m0 >> 11, sl = (m0 >> 7) & 15;
        int bh = bb * 8 + hh;
        bf16* KT = (bf16*)As;        // [64][128] bf16, XOR-swizzled rows
        bf16* VT = KT + 8192;
        const float* bias = (wc == 0) ? (bk + hh * 64) : (bv + hh * 64);
        bf16* base = (wc == 0) ? KT : VT;
#pragma unroll
        for (int m = 0; m < 4; ++m) {
            int r0 = wr * 64 + m * 16 + rg;
#pragma unroll
            for (int n = 0; n < 4; ++n) {
                int col = n * 16 + la;
                float bv_ = bias[col];
                ushort4 pk;
                unsigned short* pp = (unsigned short*)&pk;
#pragma unroll
                for (int j = 0; j < 4; ++j) {
                    float v = acc[m][n][j] + bv_;
                    if (wc == 0) v = elu1(v);
                    pp[j] = f2bu(v);
                }
                int byteoff = col * 256 + ((r0 * 2) ^ ((col & 7) << 4));
                *(ushort4*)((char*)base + byteoff) = pk;
            }
        }
        __syncthreads();
        f32x4 acc2[4] = {};
        int fe = wid;
#pragma unroll
        for (int kk = 0; kk < 4; ++kk) {
            int kbyte = kk * 64 + ka * 16;
            int ar = fe * 16 + la;
            bf16x8 av = *(const bf16x8*)((char*)VT + ar * 256 + (kbyte ^ ((ar & 7) << 4)));
#pragma unroll
            for (int fd = 0; fd < 4; ++fd) {
                int br = fd * 16 + la;
                bf16x8 bk8 = *(const bf16x8*)((char*)KT + br * 256 + (kbyte ^ ((br & 7) << 4)));
                acc2[fd] = __builtin_amdgcn_mfma_f32_16x16x32_bf16(av, bk8, acc2[fd], 0, 0, 0);
            }
        }
        bf16* dst = KVTp + (size_t)(bh * 16 + sl) * 4096;
#pragma unroll
        for (int fd = 0; fd < 4; ++fd)
#pragma unroll
            for (int j = 0; j < 4; ++j)
                dst[(fe * 16 + rg + j) * 64 + fd * 16 + la] = __float2bfloat16(acc2[fd][j]);
        if (tid < 64) {
            float s = 0.f;
#pragma unroll
            for (int rc = 0; rc < 16; ++rc) {
                bf16x8 kv8 = *(const bf16x8*)((char*)KT + tid * 256 + ((rc * 16) ^ ((tid & 7) << 4)));
#pragma unroll
                for (int j = 0; j < 8; ++j) s += (float)kv8[j];
            }
            KSp[(size_t)(bh * 16 + sl) * 64 + tid] = s;
        }
    }
}

// ------- BMxBN bf16 MFMA GEMM, BK=64, dbuf, XCD+LDS-swizzled --------------
// EPI 0: fp32 out + bf16 resid. EPI 2: bf16 out + bf16 resid. EPI 3: relu bf16.
template<int BM, int BN, int EPI>
__global__ __launch_bounds__(256) void mfma_gemm(
    const bf16* __restrict__ A, const bf16* __restrict__ Bt,
    const float* __restrict__ b0, const bf16* __restrict__ resid,
    void* __restrict__ O0, int N, int K, int GX)
{
    constexpr int MW = BM / 32;
    constexpr int NW = BN / 32;
    __shared__ __align__(16) bf16 As[2][BM * 64];
    __shared__ __align__(16) bf16 Bs[2][BN * 64];
    int tid = threadIdx.x;
    int lane = tid & 63, wid = tid >> 6;
    int wr = wid >> 1, wc = wid & 1;
    int cpx = gridDim.x >> 3;
    int work = (blockIdx.x & 7) * cpx + (blockIdx.x >> 3);
    int bx = work % GX, by = work / GX;
    int m0 = by * BM, n0 = bx * BN;
    int sr = tid >> 3;
    int scb = (((tid & 7) << 4) ^ ((sr & 7) << 4)) >> 1;   // swizzled src col
    const bf16* ga = A  + (size_t)(m0 + sr) * K + scb;
    const bf16* gb = Bt + (size_t)(n0 + sr) * K + scb;
    f32x4 acc[MW][NW] = {};
    int la = lane & 15, ka = lane >> 4;
    int xo = (la & 7) << 4;
    int nt = K >> 6;

#pragma unroll
    for (int j = 0; j < MW; ++j)
        gl16(ga + (size_t)j * 32 * K, &As[0][tid * 8 + j * 2048]);
#pragma unroll
    for (int j = 0; j < NW; ++j)
        gl16(gb + (size_t)j * 32 * K, &Bs[0][tid * 8 + j * 2048]);
    __syncthreads();

    for (int t = 0; t < nt; ++t) {
        int cur = t & 1;
        if (t + 1 < nt) {
            int k0 = (t + 1) << 6;
#pragma unroll
            for (int j = 0; j < MW; ++j)
                gl16(ga + (size_t)j * 32 * K + k0, &As[cur ^ 1][tid * 8 + j * 2048]);
#pragma unroll
            for (int j = 0; j < NW; ++j)
                gl16(gb + (size_t)j * 32 * K + k0, &Bs[cur ^ 1][tid * 8 + j * 2048]);
        }
        const char* Ab = (const char*)As[cur];
        const char* Bb = (const char*)Bs[cur];
        bf16x8 a[2][MW], b[2][NW];
#pragma unroll
        for (int kk = 0; kk < 2; ++kk) {
            int kb = (kk * 64 + ka * 16) ^ xo;
#pragma unroll
            for (int m = 0; m < MW; ++m)
                a[kk][m] = *(const bf16x8*)(Ab + (wr * (BM/2) + m * 16 + la) * 128 + kb);
#pragma unroll
            for (int n = 0; n < NW; ++n)
                b[kk][n] = *(const bf16x8*)(Bb + (wc * (BN/2) + n * 16 + la) * 128 + kb);
        }
#pragma unroll
        for (int kk = 0; kk < 2; ++kk)
#pragma unroll
            for (int m = 0; m < MW; ++m)
#pragma unroll
                for (int n = 0; n < NW; ++n)
                    acc[m][n] = __builtin_amdgcn_mfma_f32_16x16x32_bf16(a[kk][m], b[kk][n], acc[m][n], 0, 0, 0);
        __syncthreads();
    }

    int rg = (lane >> 4) * 4;
#pragma unroll
    for (int m = 0; m < MW; ++m) {
        int gm = m0 + wr * (BM/2) + m * 16 + rg;
#pragma unroll
        for (int n = 0; n < NW; ++n) {
            int gn = n0 + wc * (BN/2) + n * 16 + la;
            float bv_ = b0[gn];
#pragma unroll
            for (int j = 0; j < 4; ++j) {
                float v = acc[m][n][j] + bv_;
                if (EPI == 3) v = fmaxf(v, 0.f);
                if ((EPI == 0 || EPI == 2) && resid)
                    v += (float)resid[(size_t)(gm + j) * N + gn];
                if (EPI == 0) ((float*)O0)[(size_t)(gm + j) * N + gn] = v;
                else          ((bf16*)O0)[(size_t)(gm + j) * N + gn] = __float2bfloat16(v);
            }
        }
    }
}

// ---- attn: out[128 rows, head] = (Q_h @ KV_h) / (Q_h . ksum_h + 1e-5) ----
// KVT (bf16 partials) / KS reduced over NSLICE in fp32 during the LDS load.
__global__ __launch_bounds__(256) void attn_gemm(
    const bf16* __restrict__ Q, const bf16* __restrict__ KVTp,
    const float* __restrict__ KSp, bf16* __restrict__ out)
{
    __shared__ __align__(16) bf16 As[128][72];
    __shared__ __align__(16) bf16 Bs[64][72];
    __shared__ float ks[64];
    __shared__ float dn[128];
    int h = blockIdx.x;
    int m0 = blockIdx.y * 128;
    int bh = ((m0 >> 11) << 3) + h;
    int tid = threadIdx.x;
    int lane = tid & 63, wid = tid >> 6;
    {
        int r = tid >> 3, c0 = (tid & 7) * 8;
#pragma unroll
        for (int p = 0; p < 4; ++p) {
            int row = p * 32 + r;
            *(bf16x8*)&As[row][c0] =
                *(const bf16x8*)(Q + (size_t)(m0 + row) * DIM + h * HD + c0);
        }
        const bf16* kvb = KVTp + (size_t)bh * 16 * 4096;
        int e = tid & 63, d0 = (tid >> 6) * 16;
        float s_[16] = {};
#pragma unroll
        for (int sl = 0; sl < NSLICE; ++sl) {
            const bf16* p = kvb + sl * 4096 + e * 64 + d0;
            bf16x8 u0 = *(const bf16x8*)p;
            bf16x8 u1 = *(const bf16x8*)(p + 8);
#pragma unroll
            for (int i = 0; i < 8; ++i) { s_[i] += (float)u0[i]; s_[8 + i] += (float)u1[i]; }
        }
#pragma unroll
        for (int i = 0; i < 16; ++i)
            Bs[e][d0 + i] = __float2bfloat16(s_[i]);   // Bs[e][d] = KV[d][e]
        if (tid < 64) {
            float s = 0.f;
#pragma unroll
            for (int sl = 0; sl < NSLICE; ++sl)
                s += KSp[(size_t)(bh * 16 + sl) * 64 + tid];
            ks[tid] = s;
        }
    }
    __syncthreads();
    if (tid < 128) {
        float s = 0.f;
#pragma unroll
        for (int c = 0; c < 8; ++c) {
            bf16x8 qv = *(const bf16x8*)&As[tid][c * 8];
#pragma unroll
            for (int j = 0; j < 8; ++j)
                s += (float)qv[j] * ks[c * 8 + j];
        }
        dn[tid] = 1.f / (s + 1e-5f);
    }
    int la = lane & 15, ka = lane >> 4;
    f32x4 acc[2][4] = {};
#pragma unroll
    for (int s = 0; s < 2; ++s) {
        bf16x8 a[2], b[4];
#pragma unroll
        for (int m = 0; m < 2; ++m)
            a[m] = *(const bf16x8*)&As[wid * 32 + m * 16 + la][s * 32 + ka * 8];
#pragma unroll
        for (int n = 0; n < 4; ++n)
            b[n] = *(const bf16x8*)&Bs[n * 16 + la][s * 32 + ka * 8];
#pragma unroll
        for (int m = 0; m < 2; ++m)
#pragma unroll
            for (int n = 0; n < 4; ++n)
                acc[m][n] = __builtin_amdgcn_mfma_f32_16x16x32_bf16(a[m], b[n], acc[m][n], 0, 0, 0);
    }
    __syncthreads();
    int rg = (lane >> 4) * 4;
#pragma unroll
    for (int m = 0; m < 2; ++m) {
#pragma unroll
        for (int j = 0; j < 4; ++j) {
            int lr = wid * 32 + m * 16 + rg + j;
            float rdn = dn[lr];
            int gm = m0 + lr;
#pragma unroll
            for (int n = 0; n < 4; ++n) {
                int gn = h * HD + n * 16 + la;
                out[(size_t)gm * DIM + gn] = __float2bfloat16(acc[m][n][j] * rdn);
            }
        }
    }
}

extern "C" void kernel_launch(void* const* d_in, const int* in_sizes, int n_in,
                              void* d_out, int out_size, void* d_ws, size_t ws_size,
                              hipStream_t stream)
{
    const float* x   = (const float*)d_in[0];
    const float* Wq  = (const float*)d_in[1];
    const float* bq  = (const float*)d_in[2];
    const float* Wk  = (const float*)d_in[3];
    const float* bk  = (const float*)d_in[4];
    const float* Wv  = (const float*)d_in[5];
    const float* bv  = (const float*)d_in[6];
    const float* Wo  = (const float*)d_in[7];
    const float* bo  = (const float*)d_in[8];
    const float* W1  = (const float*)d_in[9];
    const float* b1  = (const float*)d_in[10];
    const float* W2  = (const float*)d_in[11];
    const float* b2  = (const float*)d_in[12];
    const float* g1  = (const float*)d_in[13];
    const float* be1 = (const float*)d_in[14];
    const float* g2  = (const float*)d_in[15];
    const float* be2 = (const float*)d_in[16];

    char* wsb = (char*)d_ws;
    const size_t MB = 1u << 20;
    bf16*  Qb  = (bf16*)(wsb + 0 * MB);      // 8 MB
    bf16*  xn  = (bf16*)(wsb + 8 * MB);      // 8 MB; attnb reuses after QKV
    bf16*  yb  = (bf16*)(wsb + 16 * MB);     // 8 MB
    bf16*  hb  = (bf16*)(wsb + 24 * MB);     // 8 MB
    bf16*  WqkvT = (bf16*)(wsb + 32 * MB);   // [1536][512] = 1.5 MB (permuted)
    bf16*  WoT = WqkvT + 1536 * 512;         // 0.5 MB
    bf16*  W1T = WoT + 512 * 512;            // 1 MB  [1024][512]
    bf16*  W2T = W1T + 1024 * 512;           // 1 MB  [512][1024]
    bf16*  KVTp = (bf16*)(wsb + 40 * MB);    // 32*16*4096*2 = 4 MB
    float* KSp  = (float*)(wsb + 44 * MB);   // 128 KB
    bf16*  xb   = (bf16*)(wsb + 45 * MB);    // 8 MB (bf16 copy of x)
    bf16*  F1  = (bf16*)(wsb + 0 * MB);      // 16 MB (over Qb+xn, free then)
    bf16*  attnb = xn;

    float* out = (float*)d_out;
    dim3 blk(256);

    // 0. weights -> bf16 [N][K] (qkv permuted) + xn = LN1(x) + xb
    prep_kernel<<<4096, blk, 0, stream>>>(Wq, Wk, Wv, Wo, W1, W2,
                                          WqkvT, WoT, W1T, W2T, x, g1, be1, xn, xb);
    // 1. fused q/k/v projection + per-slice KV^T/ksum (768 blocks)
    qkv_kv_kernel<<<768, blk, 0, stream>>>(xn, WqkvT, bq, bk, bv,
                                           Qb, KVTp, KSp, 0.125f);
    // 2. attn (denom + slice-reduction fused)
    attn_gemm<<<dim3(8, 64), blk, 0, stream>>>(Qb, KVTp, KSp, attnb);
    // 3. y = xb + attn @ Wo + bo  (bf16 out, bf16 resid; 128x64, 512 blocks)
    mfma_gemm<128, 64, 2><<<512, blk, 0, stream>>>(
        attnb, WoT, bo, xb, yb, 512, 512, 8);
    // 4. h = LN2(yb)
    ln_kernel<<<2048, blk, 0, stream>>>(yb, g2, be2, hb);
    // 5. f1 = relu(h @ W1 + b1)  (128x128, 512 blocks)
    mfma_gemm<128, 128, 3><<<512, blk, 0, stream>>>(
        hb, W1T, b1, nullptr, F1, 1024, 512, 8);
    // 6. out = yb + f1 @ W2 + b2  (fp32 out, bf16 resid; 128x64, 512 blocks)
    mfma_gemm<128, 64, 0><<<512, blk, 0, stream>>>(
        F1, W2T, b2, yb, out, 512, 1024, 8);
}

// Round 14
// 111.983 us; speedup vs baseline: 1.0653x; 1.0653x over previous
//
#include <hip/hip_runtime.h>
#include <hip/hip_bf16.h>
#include <math.h>

#define DIM 512
#define HEADS 8
#define HD 64
#define ROWS_TOTAL 8192   // 4 * 2048
#define SEQ 2048
#define NSLICE 16         // m-tiles (128 rows) per batch = KV partial slices

typedef __hip_bfloat16 bf16;
typedef __bf16 bf16x8 __attribute__((ext_vector_type(8)));
typedef float f32x4 __attribute__((ext_vector_type(4)));

__device__ __forceinline__ float elu1(float x) {
    return x > 0.f ? x + 1.f : __expf(x);
}
__device__ __forceinline__ void gl16(const void* g, void* l) {
    __builtin_amdgcn_global_load_lds(
        (const __attribute__((address_space(1))) void*)g,
        (__attribute__((address_space(3))) void*)l, 16, 0, 0);
}
__device__ __forceinline__ unsigned short f2bu(float v) {
    bf16 t = __float2bfloat16(v);
    return *(unsigned short*)&t;
}

// ---- prep: blocks 0..2047 transpose+convert weights; 2048..4095 LN1(x)+xb -
// WqkvT rows: [0,512) = Wq^T; row 512 + h*128 + i: i<64 -> Wk^T[h*64+i],
// i>=64 -> Wv^T[h*64+i-64]  (one 128-wide GEMM block = head h's K|V cols)
__global__ __launch_bounds__(256) void prep_kernel(
    const float* __restrict__ Wq, const float* __restrict__ Wk,
    const float* __restrict__ Wv, const float* __restrict__ Wo,
    const float* __restrict__ W1, const float* __restrict__ W2,
    bf16* WqkvT, bf16* WoT, bf16* W1T, bf16* W2T,
    const float* __restrict__ x, const float* __restrict__ g,
    const float* __restrict__ b, bf16* __restrict__ xout,
    bf16* __restrict__ xb)
{
    __shared__ float t[32][33];
    int bx = blockIdx.x;
    if (bx >= 2048) {
        int row  = (bx - 2048) * 4 + (threadIdx.x >> 6);
        int lane = threadIdx.x & 63;
        const float* xr = x + (size_t)row * DIM + lane * 8;
        float4 v1 = *(const float4*)xr;
        float4 v2 = *(const float4*)(xr + 4);
        float f[8] = {v1.x, v1.y, v1.z, v1.w, v2.x, v2.y, v2.z, v2.w};
        int c = lane * 8;
        bf16 rb[8];
#pragma unroll
        for (int j = 0; j < 8; ++j) rb[j] = __float2bfloat16(f[j]);
        *(uint4*)(xb + (size_t)row * DIM + c) = *(uint4*)rb;
        float s = 0.f, sq = 0.f;
#pragma unroll
        for (int j = 0; j < 8; ++j) { s += f[j]; sq += f[j]*f[j]; }
#pragma unroll
        for (int off = 32; off > 0; off >>= 1) {
            s  += __shfl_xor(s,  off, 64);
            sq += __shfl_xor(sq, off, 64);
        }
        float mean = s * (1.f / DIM);
        float var  = sq * (1.f / DIM) - mean * mean;
        float rstd = rsqrtf(var + 1e-5f);
        float4 ga = *(const float4*)(g + c);
        float4 gb = *(const float4*)(g + c + 4);
        float4 ba = *(const float4*)(b + c);
        float4 bb = *(const float4*)(b + c + 4);
        float gg[8]  = {ga.x,ga.y,ga.z,ga.w,gb.x,gb.y,gb.z,gb.w};
        float bbv[8] = {ba.x,ba.y,ba.z,ba.w,bb.x,bb.y,bb.z,bb.w};
        bf16 ob[8];
#pragma unroll
        for (int j = 0; j < 8; ++j)
            ob[j] = __float2bfloat16((f[j] - mean) * rstd * gg[j] + bbv[j]);
        *(uint4*)(xout + (size_t)row * DIM + c) = *(uint4*)ob;
        return;
    }
    const float* W; bf16* T; int K, N, tk, tn, mode = 0;
    if (bx < 1024) {
        int m = bx >> 8, tix = bx & 255;
        const float* ws_[4] = {Wq, Wk, Wv, Wo};
        W = ws_[m];
        T = (m == 3) ? WoT : WqkvT;
        mode = (m == 1) ? 1 : (m == 2 ? 2 : 0);
        K = 512; N = 512; tn = tix & 15; tk = tix >> 4;
    } else if (bx < 1536) {
        int tix = bx - 1024; W = W1; T = W1T; K = 512; N = 1024; tn = tix & 31; tk = tix >> 5;
    } else {
        int tix = bx - 1536; W = W2; T = W2T; K = 1024; N = 512; tn = tix & 15; tk = tix >> 4;
    }
    int n0 = tn * 32, k0 = tk * 32;
    int tx = threadIdx.x & 31, ty = threadIdx.x >> 5;
#pragma unroll
    for (int i = 0; i < 32; i += 8)
        t[ty + i][tx] = W[(size_t)(k0 + ty + i) * N + n0 + tx];
    __syncthreads();
#pragma unroll
    for (int i = 0; i < 32; i += 8) {
        int n = n0 + ty + i;
        int dr = n;
        if (mode == 1)      dr = 512 + ((n >> 6) << 7) + (n & 63);
        else if (mode == 2) dr = 576 + ((n >> 6) << 7) + (n & 63);
        T[(size_t)dr * K + k0 + tx] = __float2bfloat16(t[tx][ty + i]);
    }
}

// ------- LayerNorm (bf16 in), one wave per row ----------------------------
__global__ __launch_bounds__(256) void ln_kernel(const bf16* __restrict__ xv,
                                                 const float* __restrict__ g,
                                                 const float* __restrict__ b,
                                                 bf16* __restrict__ out)
{
    int row  = blockIdx.x * 4 + (threadIdx.x >> 6);
    int lane = threadIdx.x & 63;
    bf16x8 v = *(const bf16x8*)(xv + (size_t)row * DIM + lane * 8);
    float f[8];
#pragma unroll
    for (int j = 0; j < 8; ++j) f[j] = (float)v[j];
    float s = 0.f, sq = 0.f;
#pragma unroll
    for (int j = 0; j < 8; ++j) { s += f[j]; sq += f[j]*f[j]; }
#pragma unroll
    for (int off = 32; off > 0; off >>= 1) {
        s  += __shfl_xor(s,  off, 64);
        sq += __shfl_xor(sq, off, 64);
    }
    float mean = s * (1.f / DIM);
    float var  = sq * (1.f / DIM) - mean * mean;
    float rstd = rsqrtf(var + 1e-5f);
    int c = lane * 8;
    float4 ga = *(const float4*)(g + c);
    float4 gb = *(const float4*)(g + c + 4);
    float4 ba = *(const float4*)(b + c);
    float4 bb = *(const float4*)(b + c + 4);
    float gg[8]  = {ga.x,ga.y,ga.z,ga.w,gb.x,gb.y,gb.z,gb.w};
    float bbv[8] = {ba.x,ba.y,ba.z,ba.w,bb.x,bb.y,bb.z,bb.w};
    bf16 ob[8];
#pragma unroll
    for (int j = 0; j < 8; ++j)
        ob[j] = __float2bfloat16((f[j] - mean) * rstd * gg[j] + bbv[j]);
    *(uint4*)(out + (size_t)row * DIM + c) = *(uint4*)ob;
}

// ---- fused QKV projection + per-slice KV^T/ksum (K,V never hit HBM) ------
// m97 geometry: 128x128 tile, BK=32, 32 KB LDS (2-buffer dbuf, linear layout
// — 64B rows are bank-conflict-free at b128 granularity). KV-transpose
// epilogue reuses the staging LDS (KT+VT = 32 KB exactly).
__global__ __launch_bounds__(256) void qkv_kv_kernel(
    const bf16* __restrict__ A, const bf16* __restrict__ Bt,
    const float* __restrict__ bq, const float* __restrict__ bk,
    const float* __restrict__ bv, bf16* __restrict__ Qb,
    bf16* __restrict__ KVTp, float* __restrict__ KSp, float scale)
{
    constexpr int K = 512;
    __shared__ __align__(16) bf16 SH[16384];   // 32 KB
    int tid = threadIdx.x;
    int lane = tid & 63, wid = tid >> 6;
    int wr = wid >> 1, wc = wid & 1;
    int cpx = gridDim.x >> 3;
    int work = (blockIdx.x & 7) * cpx + (blockIdx.x >> 3);
    int bx = work % 12, by = work / 12;
    int m0 = by * 128, n0 = bx * 128;
    int sr = tid >> 2, sc = (tid & 3) * 8;     // staging: row 0..63, col chunk
    const bf16* ga = A  + (size_t)(m0 + sr) * K + sc;
    const bf16* gb = Bt + (size_t)(n0 + sr) * K + sc;
    f32x4 acc[4][4] = {};
    int la = lane & 15, ka = lane >> 4;

    // stage K-tile k0 into buffer buf: A rows 0-127, B rows 0-127 (BK=32)
    {
        gl16(ga, &SH[tid * 8]);
        gl16(ga + (size_t)64 * K, &SH[tid * 8 + 2048]);
        gl16(gb, &SH[8192 + tid * 8]);
        gl16(gb + (size_t)64 * K, &SH[8192 + tid * 8 + 2048]);
    }
    __syncthreads();
    for (int t = 0; t < 16; ++t) {
        int cur = t & 1;
        if (t + 1 < 16) {
            int k0 = (t + 1) << 5;
            bf16* As_ = SH + (cur ^ 1) * 4096;
            bf16* Bs_ = SH + 8192 + (cur ^ 1) * 4096;
            gl16(ga + k0, &As_[tid * 8]);
            gl16(ga + (size_t)64 * K + k0, &As_[tid * 8 + 2048]);
            gl16(gb + k0, &Bs_[tid * 8]);
            gl16(gb + (size_t)64 * K + k0, &Bs_[tid * 8 + 2048]);
        }
        const bf16* As_ = SH + cur * 4096;
        const bf16* Bs_ = SH + 8192 + cur * 4096;
        bf16x8 a[4], b[4];
#pragma unroll
        for (int m = 0; m < 4; ++m)
            a[m] = *(const bf16x8*)&As_[(wr * 64 + m * 16 + la) * 32 + ka * 8];
#pragma unroll
        for (int n = 0; n < 4; ++n)
            b[n] = *(const bf16x8*)&Bs_[(wc * 64 + n * 16 + la) * 32 + ka * 8];
#pragma unroll
        for (int m = 0; m < 4; ++m)
#pragma unroll
            for (int n = 0; n < 4; ++n)
                acc[m][n] = __builtin_amdgcn_mfma_f32_16x16x32_bf16(a[m], b[n], acc[m][n], 0, 0, 0);
        __syncthreads();
    }

    int rg = (lane >> 4) * 4;
    if (bx < 4) {
#pragma unroll
        for (int m = 0; m < 4; ++m) {
            int gm = m0 + wr * 64 + m * 16 + rg;
#pragma unroll
            for (int n = 0; n < 4; ++n) {
                int gnl = bx * 128 + wc * 64 + n * 16 + la;
                float bv_ = bq[gnl];
#pragma unroll
                for (int j = 0; j < 4; ++j) {
                    float v = elu1((acc[m][n][j] + bv_) * scale);
                    Qb[(size_t)(gm + j) * 512 + gnl] = __float2bfloat16(v);
                }
            }
        }
    } else {
        // ---- K|V epilogue -> swizzled LDS transpose -> KV^T + ksum ----
        int hh = bx - 4;
        int bb = m0 >> 11, sl = (m0 >> 7) & 15;
        int bh = bb * 8 + hh;
        bf16* KT = SH;               // [64][128] bf16, XOR-swizzled rows
        bf16* VT = SH + 8192;
        const float* bias = (wc == 0) ? (bk + hh * 64) : (bv + hh * 64);
        bf16* base = (wc == 0) ? KT : VT;
#pragma unroll
        for (int m = 0; m < 4; ++m) {
            int r0 = wr * 64 + m * 16 + rg;
#pragma unroll
            for (int n = 0; n < 4; ++n) {
                int col = n * 16 + la;
                float bv_ = bias[col];
                ushort4 pk;
                unsigned short* pp = (unsigned short*)&pk;
#pragma unroll
                for (int j = 0; j < 4; ++j) {
                    float v = acc[m][n][j] + bv_;
                    if (wc == 0) v = elu1(v);
                    pp[j] = f2bu(v);
                }
                int byteoff = col * 256 + ((r0 * 2) ^ ((col & 7) << 4));
                *(ushort4*)((char*)base + byteoff) = pk;
            }
        }
        __syncthreads();
        f32x4 acc2[4] = {};
        int fe = wid;
#pragma unroll
        for (int kk = 0; kk < 4; ++kk) {
            int kbyte = kk * 64 + ka * 16;
            int ar = fe * 16 + la;
            bf16x8 av = *(const bf16x8*)((char*)VT + ar * 256 + (kbyte ^ ((ar & 7) << 4)));
#pragma unroll
            for (int fd = 0; fd < 4; ++fd) {
                int br = fd * 16 + la;
                bf16x8 bk8 = *(const bf16x8*)((char*)KT + br * 256 + (kbyte ^ ((br & 7) << 4)));
                acc2[fd] = __builtin_amdgcn_mfma_f32_16x16x32_bf16(av, bk8, acc2[fd], 0, 0, 0);
            }
        }
        bf16* dst = KVTp + (size_t)(bh * 16 + sl) * 4096;
#pragma unroll
        for (int fd = 0; fd < 4; ++fd)
#pragma unroll
            for (int j = 0; j < 4; ++j)
                dst[(fe * 16 + rg + j) * 64 + fd * 16 + la] = __float2bfloat16(acc2[fd][j]);
        if (tid < 64) {
            float s = 0.f;
#pragma unroll
            for (int rc = 0; rc < 16; ++rc) {
                bf16x8 kv8 = *(const bf16x8*)((char*)KT + tid * 256 + ((rc * 16) ^ ((tid & 7) << 4)));
#pragma unroll
                for (int j = 0; j < 8; ++j) s += (float)kv8[j];
            }
            KSp[(size_t)(bh * 16 + sl) * 64 + tid] = s;
        }
    }
}

// ------- BMxBN bf16 MFMA GEMM, BK=64, dbuf, XCD+LDS-swizzled --------------
// EPI 0: fp32 out + bf16 resid. EPI 2: bf16 out + bf16 resid. EPI 3: relu bf16.
template<int BM, int BN, int EPI>
__global__ __launch_bounds__(256) void mfma_gemm(
    const bf16* __restrict__ A, const bf16* __restrict__ Bt,
    const float* __restrict__ b0, const bf16* __restrict__ resid,
    void* __restrict__ O0, int N, int K, int GX)
{
    constexpr int MW = BM / 32;
    constexpr int NW = BN / 32;
    __shared__ __align__(16) bf16 As[2][BM * 64];
    __shared__ __align__(16) bf16 Bs[2][BN * 64];
    int tid = threadIdx.x;
    int lane = tid & 63, wid = tid >> 6;
    int wr = wid >> 1, wc = wid & 1;
    int cpx = gridDim.x >> 3;
    int work = (blockIdx.x & 7) * cpx + (blockIdx.x >> 3);
    int bx = work % GX, by = work / GX;
    int m0 = by * BM, n0 = bx * BN;
    int sr = tid >> 3;
    int scb = (((tid & 7) << 4) ^ ((sr & 7) << 4)) >> 1;   // swizzled src col
    const bf16* ga = A  + (size_t)(m0 + sr) * K + scb;
    const bf16* gb = Bt + (size_t)(n0 + sr) * K + scb;
    f32x4 acc[MW][NW] = {};
    int la = lane & 15, ka = lane >> 4;
    int xo = (la & 7) << 4;
    int nt = K >> 6;

#pragma unroll
    for (int j = 0; j < MW; ++j)
        gl16(ga + (size_t)j * 32 * K, &As[0][tid * 8 + j * 2048]);
#pragma unroll
    for (int j = 0; j < NW; ++j)
        gl16(gb + (size_t)j * 32 * K, &Bs[0][tid * 8 + j * 2048]);
    __syncthreads();

    for (int t = 0; t < nt; ++t) {
        int cur = t & 1;
        if (t + 1 < nt) {
            int k0 = (t + 1) << 6;
#pragma unroll
            for (int j = 0; j < MW; ++j)
                gl16(ga + (size_t)j * 32 * K + k0, &As[cur ^ 1][tid * 8 + j * 2048]);
#pragma unroll
            for (int j = 0; j < NW; ++j)
                gl16(gb + (size_t)j * 32 * K + k0, &Bs[cur ^ 1][tid * 8 + j * 2048]);
        }
        const char* Ab = (const char*)As[cur];
        const char* Bb = (const char*)Bs[cur];
        bf16x8 a[2][MW], b[2][NW];
#pragma unroll
        for (int kk = 0; kk < 2; ++kk) {
            int kb = (kk * 64 + ka * 16) ^ xo;
#pragma unroll
            for (int m = 0; m < MW; ++m)
                a[kk][m] = *(const bf16x8*)(Ab + (wr * (BM/2) + m * 16 + la) * 128 + kb);
#pragma unroll
            for (int n = 0; n < NW; ++n)
                b[kk][n] = *(const bf16x8*)(Bb + (wc * (BN/2) + n * 16 + la) * 128 + kb);
        }
#pragma unroll
        for (int kk = 0; kk < 2; ++kk)
#pragma unroll
            for (int m = 0; m < MW; ++m)
#pragma unroll
                for (int n = 0; n < NW; ++n)
                    acc[m][n] = __builtin_amdgcn_mfma_f32_16x16x32_bf16(a[kk][m], b[kk][n], acc[m][n], 0, 0, 0);
        __syncthreads();
    }

    int rg = (lane >> 4) * 4;
#pragma unroll
    for (int m = 0; m < MW; ++m) {
        int gm = m0 + wr * (BM/2) + m * 16 + rg;
#pragma unroll
        for (int n = 0; n < NW; ++n) {
            int gn = n0 + wc * (BN/2) + n * 16 + la;
            float bv_ = b0[gn];
#pragma unroll
            for (int j = 0; j < 4; ++j) {
                float v = acc[m][n][j] + bv_;
                if (EPI == 3) v = fmaxf(v, 0.f);
                if ((EPI == 0 || EPI == 2) && resid)
                    v += (float)resid[(size_t)(gm + j) * N + gn];
                if (EPI == 0) ((float*)O0)[(size_t)(gm + j) * N + gn] = v;
                else          ((bf16*)O0)[(size_t)(gm + j) * N + gn] = __float2bfloat16(v);
            }
        }
    }
}

// ---- attn: out[128 rows, head] = (Q_h @ KV_h) / (Q_h . ksum_h + 1e-5) ----
// KVT (bf16 partials) / KS reduced over NSLICE in fp32 during the LDS load.
__global__ __launch_bounds__(256) void attn_gemm(
    const bf16* __restrict__ Q, const bf16* __restrict__ KVTp,
    const float* __restrict__ KSp, bf16* __restrict__ out)
{
    __shared__ __align__(16) bf16 As[128][72];
    __shared__ __align__(16) bf16 Bs[64][72];
    __shared__ float ks[64];
    __shared__ float dn[128];
    int h = blockIdx.x;
    int m0 = blockIdx.y * 128;
    int bh = ((m0 >> 11) << 3) + h;
    int tid = threadIdx.x;
    int lane = tid & 63, wid = tid >> 6;
    {
        int r = tid >> 3, c0 = (tid & 7) * 8;
#pragma unroll
        for (int p = 0; p < 4; ++p) {
            int row = p * 32 + r;
            *(bf16x8*)&As[row][c0] =
                *(const bf16x8*)(Q + (size_t)(m0 + row) * DIM + h * HD + c0);
        }
        const bf16* kvb = KVTp + (size_t)bh * 16 * 4096;
        int e = tid & 63, d0 = (tid >> 6) * 16;
        float s_[16] = {};
#pragma unroll
        for (int sl = 0; sl < NSLICE; ++sl) {
            const bf16* p = kvb + sl * 4096 + e * 64 + d0;
            bf16x8 u0 = *(const bf16x8*)p;
            bf16x8 u1 = *(const bf16x8*)(p + 8);
#pragma unroll
            for (int i = 0; i < 8; ++i) { s_[i] += (float)u0[i]; s_[8 + i] += (float)u1[i]; }
        }
#pragma unroll
        for (int i = 0; i < 16; ++i)
            Bs[e][d0 + i] = __float2bfloat16(s_[i]);   // Bs[e][d] = KV[d][e]
        if (tid < 64) {
            float s = 0.f;
#pragma unroll
            for (int sl = 0; sl < NSLICE; ++sl)
                s += KSp[(size_t)(bh * 16 + sl) * 64 + tid];
            ks[tid] = s;
        }
    }
    __syncthreads();
    if (tid < 128) {
        float s = 0.f;
#pragma unroll
        for (int c = 0; c < 8; ++c) {
            bf16x8 qv = *(const bf16x8*)&As[tid][c * 8];
#pragma unroll
            for (int j = 0; j < 8; ++j)
                s += (float)qv[j] * ks[c * 8 + j];
        }
        dn[tid] = 1.f / (s + 1e-5f);
    }
    int la = lane & 15, ka = lane >> 4;
    f32x4 acc[2][4] = {};
#pragma unroll
    for (int s = 0; s < 2; ++s) {
        bf16x8 a[2], b[4];
#pragma unroll
        for (int m = 0; m < 2; ++m)
            a[m] = *(const bf16x8*)&As[wid * 32 + m * 16 + la][s * 32 + ka * 8];
#pragma unroll
        for (int n = 0; n < 4; ++n)
            b[n] = *(const bf16x8*)&Bs[n * 16 + la][s * 32 + ka * 8];
#pragma unroll
        for (int m = 0; m < 2; ++m)
#pragma unroll
            for (int n = 0; n < 4; ++n)
                acc[m][n] = __builtin_amdgcn_mfma_f32_16x16x32_bf16(a[m], b[n], acc[m][n], 0, 0, 0);
    }
    __syncthreads();
    int rg = (lane >> 4) * 4;
#pragma unroll
    for (int m = 0; m < 2; ++m) {
#pragma unroll
        for (int j = 0; j < 4; ++j) {
            int lr = wid * 32 + m * 16 + rg + j;
            float rdn = dn[lr];
            int gm = m0 + lr;
#pragma unroll
            for (int n = 0; n < 4; ++n) {
                int gn = h * HD + n * 16 + la;
                out[(size_t)gm * DIM + gn] = __float2bfloat16(acc[m][n][j] * rdn);
            }
        }
    }
}

extern "C" void kernel_launch(void* const* d_in, const int* in_sizes, int n_in,
                              void* d_out, int out_size, void* d_ws, size_t ws_size,
                              hipStream_t stream)
{
    const float* x   = (const float*)d_in[0];
    const float* Wq  = (const float*)d_in[1];
    const float* bq  = (const float*)d_in[2];
    const float* Wk  = (const float*)d_in[3];
    const float* bk  = (const float*)d_in[4];
    const float* Wv  = (const float*)d_in[5];
    const float* bv  = (const float*)d_in[6];
    const float* Wo  = (const float*)d_in[7];
    const float* bo  = (const float*)d_in[8];
    const float* W1  = (const float*)d_in[9];
    const float* b1  = (const float*)d_in[10];
    const float* W2  = (const float*)d_in[11];
    const float* b2  = (const float*)d_in[12];
    const float* g1  = (const float*)d_in[13];
    const float* be1 = (const float*)d_in[14];
    const float* g2  = (const float*)d_in[15];
    const float* be2 = (const float*)d_in[16];

    char* wsb = (char*)d_ws;
    const size_t MB = 1u << 20;
    bf16*  Qb  = (bf16*)(wsb + 0 * MB);      // 8 MB
    bf16*  xn  = (bf16*)(wsb + 8 * MB);      // 8 MB; attnb reuses after QKV
    bf16*  yb  = (bf16*)(wsb + 16 * MB);     // 8 MB
    bf16*  hb  = (bf16*)(wsb + 24 * MB);     // 8 MB
    bf16*  WqkvT = (bf16*)(wsb + 32 * MB);   // [1536][512] = 1.5 MB (permuted)
    bf16*  WoT = WqkvT + 1536 * 512;         // 0.5 MB
    bf16*  W1T = WoT + 512 * 512;            // 1 MB  [1024][512]
    bf16*  W2T = W1T + 1024 * 512;           // 1 MB  [512][1024]
    bf16*  KVTp = (bf16*)(wsb + 40 * MB);    // 32*16*4096*2 = 4 MB
    float* KSp  = (float*)(wsb + 44 * MB);   // 128 KB
    bf16*  xb   = (bf16*)(wsb + 45 * MB);    // 8 MB (bf16 copy of x)
    bf16*  F1  = (bf16*)(wsb + 0 * MB);      // 16 MB (over Qb+xn, free then)
    bf16*  attnb = xn;

    float* out = (float*)d_out;
    dim3 blk(256);

    // 0. weights -> bf16 [N][K] (qkv permuted) + xn = LN1(x) + xb
    prep_kernel<<<4096, blk, 0, stream>>>(Wq, Wk, Wv, Wo, W1, W2,
                                          WqkvT, WoT, W1T, W2T, x, g1, be1, xn, xb);
    // 1. fused q/k/v projection + per-slice KV^T/ksum (768 blocks, BK=32)
    qkv_kv_kernel<<<768, blk, 0, stream>>>(xn, WqkvT, bq, bk, bv,
                                           Qb, KVTp, KSp, 0.125f);
    // 2. attn (denom + slice-reduction fused)
    attn_gemm<<<dim3(8, 64), blk, 0, stream>>>(Qb, KVTp, KSp, attnb);
    // 3. y = xb + attn @ Wo + bo  (bf16 out, bf16 resid; 64x64, 1024 blocks)
    mfma_gemm<64, 64, 2><<<1024, blk, 0, stream>>>(
        attnb, WoT, bo, xb, yb, 512, 512, 8);
    // 4. h = LN2(yb)
    ln_kernel<<<2048, blk, 0, stream>>>(yb, g2, be2, hb);
    // 5. f1 = relu(h @ W1 + b1)  (64x64, 2048 blocks)
    mfma_gemm<64, 64, 3><<<2048, blk, 0, stream>>>(
        hb, W1T, b1, nullptr, F1, 1024, 512, 16);
    // 6. out = yb + f1 @ W2 + b2  (fp32 out, bf16 resid; 64x64, 1024 blocks)
    mfma_gemm<64, 64, 0><<<1024, blk, 0, stream>>>(
        F1, W2T, b2, yb, out, 512, 1024, 8);
}